// Round 2
// baseline (2438.930 us; speedup 1.0000x reference)
//
#include <hip/hip_runtime.h>
#include <hip/hip_bf16.h>

#define HH 256
#define WW 256
#define BB 16
#define CI 32
#define CO 64
#define TH 8
#define TW 32

// workspace offsets (in floats)
#define OFF_CM   0            // colmean  [b][s][w]  16*32*256
#define OFF_RM   131072       // rowmean  [b][s][h]  16*32*256
#define OFF_XH   262144       // xh       [b][o][w]  16*64*256
#define OFF_XV   524288       // xv       [b][o][h]  16*64*256
#define OFF_W2C  786432       // W2c      [c][s]     64*32
#define OFF_B2C  788480       // b2c      [c]        64
#define OFF_LC2  788544       // lc2      [ij][s][o] 9*32*9
#define OFF_LCB2 791136       // lcb2     [ij][o]    81
#define OFF_CFT  791217       // cfT      [c][o]     64*9
#define OFF_RBT  791793       // rbT      [s][o]     32*9

__device__ __forceinline__ float tanh_f(float x) {
  float e = __expf(2.f * x);
  return 1.f - 2.f / (e + 1.f);   // safe: e->inf => 1, e->0 => -1
}

// ---------------- Pass A: column/row means of sharp (channels 0..31) --------
__global__ __launch_bounds__(256)
void pass_mean(const float* __restrict__ feat, float* __restrict__ ws)
{
  int bs = blockIdx.x;                  // b*32 + s
  const float* plane = feat + ((size_t)((bs >> 5) * CO + (bs & 31))) * (HH * WW);
  int wave = threadIdx.x >> 6, lane = threadIdx.x & 63;

  __shared__ float rowbuf[HH];
  __shared__ float cpart[4][WW];

  float c0 = 0.f, c1 = 0.f, c2 = 0.f, c3 = 0.f;
  for (int rr = 0; rr < 64; ++rr) {
    int r = wave * 64 + rr;
    float4 v = reinterpret_cast<const float4*>(plane + (size_t)r * WW)[lane];
    c0 += v.x; c1 += v.y; c2 += v.z; c3 += v.w;
    float rs = v.x + v.y + v.z + v.w;
    #pragma unroll
    for (int off = 32; off > 0; off >>= 1) rs += __shfl_down(rs, off);
    if (lane == 0) rowbuf[r] = rs;
  }
  cpart[wave][lane * 4 + 0] = c0;
  cpart[wave][lane * 4 + 1] = c1;
  cpart[wave][lane * 4 + 2] = c2;
  cpart[wave][lane * 4 + 3] = c3;
  __syncthreads();
  int t = threadIdx.x;
  float cs = cpart[0][t] + cpart[1][t] + cpart[2][t] + cpart[3][t];
  ws[OFF_CM + (size_t)bs * WW + t] = cs * (1.f / HH);
  ws[OFF_RM + (size_t)bs * HH + t] = rowbuf[t] * (1.f / WW);
}

// ---------------- Pass B1: combined weights ---------------------------------
__global__ __launch_bounds__(256)
void pass_comb(const float* __restrict__ sr_w, const float* __restrict__ sr_b,
               const float* __restrict__ sp_w, const float* __restrict__ sp_b,
               const float* __restrict__ cf_w, const float* __restrict__ lc_w,
               const float* __restrict__ rb_w, float* __restrict__ ws)
{
  int t = threadIdx.x;
  // W2c[c][s] = sum_m sp_w[c][m] * sr_w[m][s]
  for (int idx = t; idx < CO * CI; idx += 256) {
    int c = idx >> 5, s = idx & 31;
    float a = 0.f;
    for (int m = 0; m < CO; ++m) a = fmaf(sp_w[c * CO + m], sr_w[m * CI + s], a);
    ws[OFF_W2C + idx] = a;
  }
  if (t < CO) {
    float a = sp_b[t];
    for (int m = 0; m < CO; ++m) a = fmaf(sp_w[t * CO + m], sr_b[m], a);
    ws[OFF_B2C + t] = a;
  }
  // lc2[ij][s][o] = sum_c lc_w[o][c][ij] * sr_w[c][s]
  for (int idx = t; idx < 9 * CI * 9; idx += 256) {
    int ij = idx / (CI * 9);
    int r = idx - ij * (CI * 9);
    int s = r / 9, o = r - s * 9;
    float a = 0.f;
    for (int c = 0; c < CO; ++c) a = fmaf(lc_w[(o * CO + c) * 9 + ij], sr_w[c * CI + s], a);
    ws[OFF_LC2 + idx] = a;
  }
  if (t < 81) {
    int ij = t / 9, o = t - ij * 9;
    float a = 0.f;
    for (int c = 0; c < CO; ++c) a = fmaf(lc_w[(o * CO + c) * 9 + ij], sr_b[c], a);
    ws[OFF_LCB2 + t] = a;
  }
  for (int idx = t; idx < CO * 9; idx += 256) {   // cfT[c][o]
    int c = idx / 9, o = idx - c * 9;
    ws[OFF_CFT + idx] = cf_w[o * CO + c];
  }
  for (int idx = t; idx < CI * 9; idx += 256) {   // rbT[s][o]  (288 entries!)
    int s = idx / 9, o = idx - s * 9;
    ws[OFF_RBT + idx] = rb_w[o * CI + s];
  }
}

// ---------------- Pass B2: xh (y=0) / xv (y=1) ------------------------------
__global__ __launch_bounds__(256)
void pass_axis(const float* __restrict__ ch_w, const float* __restrict__ cv_w,
               float* __restrict__ ws)
{
  int b = blockIdx.x;
  int vert = blockIdx.y;
  int t = threadIdx.x;
  const float* kw   = vert ? cv_w : ch_w;                               // [o][c][tap]
  const float* mean = ws + (vert ? OFF_RM : OFF_CM) + (size_t)b * CI * 256;
  float*       outp = ws + (vert ? OFF_XV : OFF_XH) + (size_t)b * CO * 256;
  const float* W2c = ws + OFF_W2C;
  const float* b2c = ws + OFF_B2C;

  __shared__ float mL[CI][258];        // padded mean
  __shared__ float cwL[CO][CI][3];     // kw combined with W2c
  __shared__ float cbL[3][CO];         // kw combined with b2c

  for (int idx = t; idx < CI * 258; idx += 256) {
    int s = idx / 258, q = idx - s * 258;
    float v = 0.f;
    if (q >= 1 && q <= 256) v = mean[s * 256 + q - 1];
    mL[s][q] = v;
  }
  for (int idx = t; idx < CO * CI * 3; idx += 256) {
    int o = idx / (CI * 3);
    int r = idx - o * (CI * 3);
    int s = r / 3, j = r - s * 3;
    float a = 0.f;
    for (int c = 0; c < CO; ++c) a = fmaf(kw[(o * CO + c) * 3 + j], W2c[c * CI + s], a);
    cwL[o][s][j] = a;
  }
  if (t < 3 * CO) {
    int j = t / CO, o = t - j * CO;
    float a = 0.f;
    for (int c = 0; c < CO; ++c) a = fmaf(kw[(o * CO + c) * 3 + j], b2c[c], a);
    cbL[j][o] = a;
  }
  __syncthreads();
  for (int o = 0; o < CO; ++o) {
    float acc = 0.f;
    #pragma unroll
    for (int j = 0; j < 3; ++j) {
      int qq = t + j;                        // mL index (input pos t+j-1)
      float okf = (qq >= 1 && qq <= 256) ? 1.f : 0.f;
      acc = fmaf(cbL[j][o], okf, acc);
      #pragma unroll
      for (int s = 0; s < CI; ++s)
        acc = fmaf(cwL[o][s][j], mL[s][qq], acc);
    }
    outp[o * 256 + t] = acc;
  }
}

// ---------------- Pass C: fused main kernel ---------------------------------
__global__ __launch_bounds__(256, 2)
void pass_main(const float* __restrict__ feat,
               const float* __restrict__ sr_w, const float* __restrict__ sr_b,
               const float* __restrict__ lc_b, const float* __restrict__ cf_b,
               const float* __restrict__ rb_b,
               const float* __restrict__ ws,
               float* __restrict__ out1, float* __restrict__ out2)
{
  const float* W2c  = ws + OFF_W2C;
  const float* b2c  = ws + OFF_B2C;
  const float* lc2  = ws + OFF_LC2;
  const float* lcb2 = ws + OFF_LCB2;
  const float* cfT  = ws + OFF_CFT;
  const float* rbT  = ws + OFF_RBT;

  __shared__ float sh[CI][TH + 2][TW + 2];   // 43.5 KB sharp tile (+halo, zero-filled)
  __shared__ float xhL[CO][TW];              // 8 KB
  __shared__ float xvL[CO][TH];              // 2 KB

  int b  = blockIdx.z;
  int h0 = blockIdx.y * TH;
  int w0 = blockIdx.x * TW;
  int t  = threadIdx.x;
  const float* fb = feat + (size_t)b * CO * HH * WW;

  for (int idx = t; idx < CI * (TH + 2) * (TW + 2); idx += 256) {
    int s = idx / ((TH + 2) * (TW + 2));
    int r = idx - s * ((TH + 2) * (TW + 2));
    int hh = r / (TW + 2), wq = r - hh * (TW + 2);
    int gh = h0 - 1 + hh, gw = w0 - 1 + wq;
    float v = 0.f;
    if ((unsigned)gh < HH && (unsigned)gw < WW)
      v = fb[(size_t)s * (HH * WW) + gh * WW + gw];
    sh[s][hh][wq] = v;
  }
  {
    const float* xhp = ws + OFF_XH + (size_t)b * CO * WW + w0;
    for (int idx = t; idx < CO * TW; idx += 256) {
      int c = idx >> 5, wq = idx & 31;
      xhL[c][wq] = xhp[c * WW + wq];
    }
    const float* xvp = ws + OFF_XV + (size_t)b * CO * HH + h0;
    for (int idx = t; idx < CO * TH; idx += 256) {
      int c = idx >> 3, hq = idx & 7;
      xvL[c][hq] = xvp[c * HH + hq];
    }
  }
  __syncthreads();

  int ph = t >> 5, pw = t & 31;
  int h = h0 + ph, w = w0 + pw;

  // ---- local_att[9] = tanh(lc2 (*) sharp + gated bias) ----
  float att[9];
  #pragma unroll
  for (int o = 0; o < 9; ++o) att[o] = lc_b[o];
  #pragma unroll 1
  for (int ij = 0; ij < 9; ++ij) {
    int di = ij / 3, dj = ij - di * 3;                 // 0..2
    float okf = ((unsigned)(h + di - 1) < HH && (unsigned)(w + dj - 1) < WW) ? 1.f : 0.f;
    const float* lw = lc2 + ij * (CI * 9);
    #pragma unroll
    for (int s = 0; s < CI; ++s) {
      float v = sh[s][ph + di][pw + dj];
      #pragma unroll
      for (int o = 0; o < 9; ++o) att[o] = fmaf(lw[s * 9 + o], v, att[o]);
    }
    #pragma unroll
    for (int o = 0; o < 9; ++o) att[o] = fmaf(lcb2[ij * 9 + o], okf, att[o]);
  }
  #pragma unroll
  for (int o = 0; o < 9; ++o) att[o] = tanh_f(att[o]);

  // ---- gA[s] = sum_ij att[ij]*sharpPad ; asum = sum_ij att[ij]*inb ----
  float gA[CI];
  #pragma unroll
  for (int s = 0; s < CI; ++s) gA[s] = 0.f;
  float asum = 0.f;
  #pragma unroll
  for (int ij = 0; ij < 9; ++ij) {
    const int di = ij / 3, dj = ij - di * 3;
    float av = att[ij];
    float okf = ((unsigned)(h + di - 1) < HH && (unsigned)(w + dj - 1) < WW) ? 1.f : 0.f;
    asum = fmaf(av, okf, asum);
    #pragma unroll
    for (int s = 0; s < CI; ++s)
      gA[s] = fmaf(av, sh[s][ph + di][pw + dj], gA[s]);
  }

  // ---- fusion[9] = tanh(cf_w @ leaky(xh+xv) + cf_b) ----
  float fus[9];
  #pragma unroll
  for (int o = 0; o < 9; ++o) fus[o] = cf_b[o];
  #pragma unroll 4
  for (int c = 0; c < CO; ++c) {
    float tv = xhL[c][pw] + xvL[c][ph];
    tv = (tv >= 0.f) ? tv : 0.2f * tv;
    #pragma unroll
    for (int o = 0; o < 9; ++o) fus[o] = fmaf(cfT[c * 9 + o], tv, fus[o]);
  }
  #pragma unroll
  for (int o = 0; o < 9; ++o) fus[o] = tanh_f(fus[o]);

  // ---- g[s] = sum_ij fus[ij]*sharpPad ; fsum ----
  float g[CI];
  #pragma unroll
  for (int s = 0; s < CI; ++s) g[s] = 0.f;
  float fsum = 0.f;
  #pragma unroll
  for (int ij = 0; ij < 9; ++ij) {
    const int di = ij / 3, dj = ij - di * 3;
    float fv = fus[ij];
    float okf = ((unsigned)(h + di - 1) < HH && (unsigned)(w + dj - 1) < WW) ? 1.f : 0.f;
    fsum = fmaf(fv, okf, fsum);
    #pragma unroll
    for (int s = 0; s < CI; ++s)
      g[s] = fmaf(fv, sh[s][ph + di][pw + dj], g[s]);
  }

  // ---- reblur = tanh(rb_w @ blur + rb_b) ----
  float rb[9];
  #pragma unroll
  for (int o = 0; o < 9; ++o) rb[o] = rb_b[o];
  const float* fblur = fb + (size_t)CI * HH * WW + (size_t)h * WW + w;
  #pragma unroll 4
  for (int s = 0; s < CI; ++s) {
    float v = fblur[(size_t)s * HH * WW];
    #pragma unroll
    for (int o = 0; o < 9; ++o) rb[o] = fmaf(rbT[s * 9 + o], v, rb[o]);
  }
  {
    float* o1 = out1 + (size_t)b * 9 * HH * WW + (size_t)h * WW + w;
    #pragma unroll
    for (int o = 0; o < 9; ++o) o1[(size_t)o * HH * WW] = tanh_f(rb[o]);
  }

  // ---- center sharp in regs ----
  float shpC[CI];
  #pragma unroll
  for (int s = 0; s < CI; ++s) shpC[s] = sh[s][ph + 1][pw + 1];

  // ---- final: x, short, long, out2 = feature - (x*long + short) ----
  float* o2 = out2 + (size_t)b * CO * HH * WW + (size_t)h * WW + w;
  #pragma unroll 2
  for (int c = 0; c < CO; ++c) {
    float xc = sr_b[c];
    float sv = sr_b[c] * asum;
    float lv = b2c[c] * fsum;
    const float* w1 = sr_w + c * CI;
    const float* w2 = W2c + c * CI;
    #pragma unroll
    for (int s = 0; s < CI; ++s) {
      float a = w1[s];
      xc = fmaf(a, shpC[s], xc);
      sv = fmaf(a, gA[s], sv);
      lv = fmaf(w2[s], g[s], lv);
    }
    float fv = (c < CI) ? sh[c][ph + 1][pw + 1]
                        : fb[(size_t)c * HH * WW + (size_t)h * WW + w];
    o2[(size_t)c * HH * WW] = fv - fmaf(xc, lv, sv);
  }
}

extern "C" void kernel_launch(void* const* d_in, const int* in_sizes, int n_in,
                              void* d_out, int out_size, void* d_ws, size_t ws_size,
                              hipStream_t stream) {
  const float* feature = (const float*)d_in[0];
  const float* sr_w = (const float*)d_in[1];
  const float* sr_b = (const float*)d_in[2];
  const float* sp_w = (const float*)d_in[3];
  const float* sp_b = (const float*)d_in[4];
  const float* ch_w = (const float*)d_in[5];
  const float* cv_w = (const float*)d_in[6];
  const float* cf_w = (const float*)d_in[7];
  const float* cf_b = (const float*)d_in[8];
  const float* lc_w = (const float*)d_in[9];
  const float* lc_b = (const float*)d_in[10];
  const float* rb_w = (const float*)d_in[11];
  const float* rb_b = (const float*)d_in[12];

  float* wsf  = (float*)d_ws;
  float* out1 = (float*)d_out;                         // reblur (16,9,256,256)
  float* out2 = out1 + (size_t)BB * 9 * HH * WW;       // feature - attention (16,64,256,256)

  pass_mean<<<dim3(BB * CI), 256, 0, stream>>>(feature, wsf);
  pass_comb<<<dim3(1), 256, 0, stream>>>(sr_w, sr_b, sp_w, sp_b, cf_w, lc_w, rb_w, wsf);
  pass_axis<<<dim3(BB, 2), 256, 0, stream>>>(ch_w, cv_w, wsf);
  pass_main<<<dim3(WW / TW, HH / TH, BB), 256, 0, stream>>>(
      feature, sr_w, sr_b, lc_b, cf_b, rb_b, wsf, out1, out2);
}